// Round 6
// baseline (328.575 us; speedup 1.0000x reference)
//
#include <hip/hip_runtime.h>
#include <cstdint>
#include <cstddef>

// ---------------------------------------------------------------------------
// GATv2Classifier: x(N,128) -> GATv2(2 heads,64,concat) -> elu
//                 -> GATv2(1 head,64) -> elu -> mean-pool(64 graphs) -> linear(10)
// R1: pool -> run-length register accumulation (batch sorted). 1368->999us.
// R2: CSR gather + single-pass fused softmax-agg (no float atomics). 999->567us.
// R3: bf16 + MFMA GEMMs. 567->405us.
// R4: edge-parallel waves (2 edges/iter gat1, 4 gat2). 405->328us. gat1
//     VALU-bound: VALUBusy 65%, HBM 18%, ~70 wave-instr/edge.
// R5: leaky(t)=0.6t+0.4|t| -> per-node score terms precomputed (node_dot),
//     per-edge per-ch work = add + fma(|.|) only. gat1: 4 edges/iter
//     (16 lanes/edge, 8ch/lane dwordx4 gathers); gat2: 8 edges/iter.
//     3 shuffles per iter. cursor written by scan_add (memcpy dropped).
// ---------------------------------------------------------------------------

typedef __attribute__((ext_vector_type(8))) short s8v;   // 8 bf16 (4 VGPRs)
typedef __attribute__((ext_vector_type(4))) float f4v;   // MFMA accumulator

__device__ __forceinline__ unsigned short f2bf(float f) {
    unsigned u = __float_as_uint(f);
    unsigned r = (u + 0x7fffu + ((u >> 16) & 1u)) >> 16;   // RNE
    return (unsigned short)r;
}
__device__ __forceinline__ float bf2f_lo(unsigned pair) {
    return __uint_as_float(pair << 16);
}
__device__ __forceinline__ float bf2f_hi(unsigned pair) {
    return __uint_as_float(pair & 0xffff0000u);
}

// ---------------- weight packing to MFMA B-fragment layout ----------------
// B-frag 16x16x32: lane holds B[k = ks*32 + (lane>>4)*8 + j][col = ct*16 + (lane&15)]
__global__ void pack_weights(const float* __restrict__ Wl1, const float* __restrict__ Wr1,
                             const float* __restrict__ Wl2, const float* __restrict__ Wr2,
                             unsigned short* __restrict__ Wl1p, unsigned short* __restrict__ Wr1p,
                             unsigned short* __restrict__ Wl2p, unsigned short* __restrict__ Wr2p) {
    int t = blockIdx.x * blockDim.x + threadIdx.x;
    const float* W; unsigned short* Wp; int CO, base;
    if      (t < 2048) { W = Wl1; Wp = Wl1p; CO = 128; base = t; }
    else if (t < 4096) { W = Wr1; Wp = Wr1p; CO = 128; base = t - 2048; }
    else if (t < 5120) { W = Wl2; Wp = Wl2p; CO = 64;  base = t - 4096; }
    else if (t < 6144) { W = Wr2; Wp = Wr2p; CO = 64;  base = t - 5120; }
    else return;
    int lane = base & 63, ks = (base >> 6) & 3, ct = base >> 8;
    int col = ct * 16 + (lane & 15);
    int k0 = ks * 32 + (lane >> 4) * 8;
    unsigned short u[8];
#pragma unroll
    for (int j = 0; j < 8; j++) u[j] = f2bf(W[(size_t)(k0 + j) * CO + col]);
    unsigned* dst = (unsigned*)(Wp + (size_t)base * 8);
    dst[0] = u[0] | ((unsigned)u[1] << 16);
    dst[1] = u[2] | ((unsigned)u[3] << 16);
    dst[2] = u[4] | ((unsigned)u[5] << 16);
    dst[3] = u[6] | ((unsigned)u[7] << 16);
}

// ---------------- dual MFMA GEMM: outL/outR (both bf16) = A @ Wl / A @ Wr ---
template<int CO, bool A_BF16>
__global__ void gemm_dual(const void* __restrict__ Aptr,
                          const unsigned short* __restrict__ Wlp,
                          const unsigned short* __restrict__ Wrp,
                          unsigned short* __restrict__ outL,
                          unsigned short* __restrict__ outR, int n) {
    constexpr int NT = CO / 16;
    int lane = threadIdx.x & 63;
    int node0 = blockIdx.x * 64 + (threadIdx.x >> 6) * 16;
    int m = lane & 15, quad = lane >> 4;
    int row = node0 + m;
    s8v a[4];
    if (A_BF16) {
        const unsigned short* A = (const unsigned short*)Aptr;
#pragma unroll
        for (int ks = 0; ks < 4; ks++) {
            if (row < n) a[ks] = *(const s8v*)(A + (size_t)row * 128 + ks * 32 + quad * 8);
            else { union { s8v v; unsigned short u[8]; } z;
#pragma unroll
                   for (int j = 0; j < 8; j++) z.u[j] = 0; a[ks] = z.v; }
        }
    } else {
        const float* A = (const float*)Aptr;
#pragma unroll
        for (int ks = 0; ks < 4; ks++) {
            union { s8v v; unsigned short u[8]; } t;
#pragma unroll
            for (int j = 0; j < 8; j++)
                t.u[j] = (row < n) ? f2bf(A[(size_t)row * 128 + ks * 32 + quad * 8 + j]) : 0;
            a[ks] = t.v;
        }
    }
    int r0 = quad * 4;
#pragma unroll
    for (int ct = 0; ct < NT; ct++) {
        f4v cl = {0.f, 0.f, 0.f, 0.f}, cr = {0.f, 0.f, 0.f, 0.f};
#pragma unroll
        for (int ks = 0; ks < 4; ks++) {
            s8v bl = *(const s8v*)(Wlp + ((size_t)(ct * 4 + ks) * 64 + lane) * 8);
            s8v br = *(const s8v*)(Wrp + ((size_t)(ct * 4 + ks) * 64 + lane) * 8);
            cl = __builtin_amdgcn_mfma_f32_16x16x32_bf16(a[ks], bl, cl, 0, 0, 0);
            cr = __builtin_amdgcn_mfma_f32_16x16x32_bf16(a[ks], br, cr, 0, 0, 0);
        }
        int col = ct * 16 + m;           // C/D: col=lane&15, row=(lane>>4)*4+reg
#pragma unroll
        for (int r = 0; r < 4; r++) {
            int nd = node0 + r0 + r;
            if (nd < n) {
                outL[(size_t)nd * CO + col] = f2bf(cl[r]);
                outR[(size_t)nd * CO + col] = f2bf(cr[r]);
            }
        }
    }
}

// ---------------- per-node score terms: s = 0.6 * (att_h . x_h) -------------
// H=2/CO=128: lane covers 2 ch, head = lane>>5. H=1/CO=64: lane covers 1 ch.
template<int CO, int H>
__global__ void node_dot(const unsigned short* __restrict__ xl,
                         const unsigned short* __restrict__ xr,
                         const float* __restrict__ att,
                         float* __restrict__ sl06, float* __restrict__ sr06, int n) {
    int node = (blockIdx.x * blockDim.x + threadIdx.x) >> 6;
    if (node >= n) return;
    int lane = threadIdx.x & 63;
    if (CO == 128) {
        unsigned lv = *(const unsigned*)(xl + (size_t)node * 128 + lane * 2);
        unsigned rv = *(const unsigned*)(xr + (size_t)node * 128 + lane * 2);
        float a0 = att[lane * 2], a1 = att[lane * 2 + 1];
        float sl = a0 * bf2f_lo(lv) + a1 * bf2f_hi(lv);
        float sr = a0 * bf2f_lo(rv) + a1 * bf2f_hi(rv);
#pragma unroll
        for (int o = 1; o < 32; o <<= 1) {
            sl += __shfl_xor(sl, o, 64); sr += __shfl_xor(sr, o, 64);
        }
        if ((lane & 31) == 0) {
            int h = lane >> 5;
            sl06[(size_t)node * 2 + h] = 0.6f * sl;
            sr06[(size_t)node * 2 + h] = 0.6f * sr;
        }
    } else {
        float l = __uint_as_float((unsigned)xl[(size_t)node * 64 + lane] << 16);
        float r = __uint_as_float((unsigned)xr[(size_t)node * 64 + lane] << 16);
        float a = att[lane];
        float sl = a * l, sr = a * r;
#pragma unroll
        for (int o = 1; o < 64; o <<= 1) {
            sl += __shfl_xor(sl, o, 64); sr += __shfl_xor(sr, o, 64);
        }
        if (lane == 0) { sl06[node] = 0.6f * sl; sr06[node] = 0.6f * sr; }
    }
}

// ---------------- CSR build ----------------
__global__ void hist_deg(const int* __restrict__ dstA, int E, int* __restrict__ deg) {
    int i = blockIdx.x * blockDim.x + threadIdx.x;
    if (i < E) atomicAdd(&deg[dstA[i]], 1);
}

__global__ void scan_block(const int* __restrict__ deg, int n,
                           int* __restrict__ rowptr, int* __restrict__ bsums) {
    __shared__ int tmp[256];
    int i = blockIdx.x * 256 + threadIdx.x;
    int v = (i < n) ? deg[i] : 0;
    tmp[threadIdx.x] = v;
    __syncthreads();
    for (int off = 1; off < 256; off <<= 1) {
        int t = (threadIdx.x >= (unsigned)off) ? tmp[threadIdx.x - off] : 0;
        __syncthreads();
        tmp[threadIdx.x] += t;
        __syncthreads();
    }
    if (i < n) rowptr[i] = tmp[threadIdx.x] - v;           // exclusive
    if (threadIdx.x == 255) bsums[blockIdx.x] = tmp[255];
}

__global__ void scan_sums(int* __restrict__ bsums, int nb) {
    __shared__ int tmp[256];
    int v = (threadIdx.x < (unsigned)nb) ? bsums[threadIdx.x] : 0;
    tmp[threadIdx.x] = v;
    __syncthreads();
    for (int off = 1; off < 256; off <<= 1) {
        int t = (threadIdx.x >= (unsigned)off) ? tmp[threadIdx.x - off] : 0;
        __syncthreads();
        tmp[threadIdx.x] += t;
        __syncthreads();
    }
    if (threadIdx.x < (unsigned)nb) bsums[threadIdx.x] = tmp[threadIdx.x] - v;
}

__global__ void scan_add(int* __restrict__ rowptr, int* __restrict__ cursor,
                         const int* __restrict__ bsums, int n, int E) {
    int i = blockIdx.x * 256 + threadIdx.x;
    if (i < n) {
        int v = rowptr[i] + bsums[i >> 8];
        rowptr[i] = v;
        cursor[i] = v;
    }
    if (i == n) rowptr[n] = E;
}

__global__ void csr_fill(const int* __restrict__ srcA, const int* __restrict__ dstA,
                         int E, int* __restrict__ cursor, int* __restrict__ csr_src) {
    int i = blockIdx.x * blockDim.x + threadIdx.x;
    if (i < E) {
        int pos = atomicAdd(&cursor[dstA[i]], 1);
        csr_src[pos] = srcA[i];
    }
}

// ---------------- fused GATv2 layer 1: 4 edges/iter --------------------------
// lane = [e:2][h:1][g:3]; 16 lanes/edge (2 heads x 8 lanes x 8ch dwordx4).
// e = sl06[s,h] + sr06[d,h] + sum_c (0.4 a_c)|xl_c + xr_c|; 3 shuffles/iter.
__global__ void gat1_fused(const unsigned short* __restrict__ xl,
                           const unsigned short* __restrict__ xr,
                           const float* __restrict__ sl06, const float* __restrict__ sr06,
                           const float* __restrict__ att, const float* __restrict__ bias,
                           const int* __restrict__ rowptr, const int* __restrict__ csr_src,
                           unsigned short* __restrict__ h1, int n) {
    int d = (blockIdx.x * blockDim.x + threadIdx.x) >> 6;
    if (d >= n) return;
    int lane = threadIdx.x & 63;
    int e = lane >> 4;                  // edge slot 0..3
    int h = (lane >> 3) & 1;            // head
    int off = h * 64 + (lane & 7) * 8;  // 8-channel base
    uint4 xv = *(const uint4*)(xr + (size_t)d * 128 + off);
    float x0 = bf2f_lo(xv.x), x1 = bf2f_hi(xv.x);
    float x2 = bf2f_lo(xv.y), x3 = bf2f_hi(xv.y);
    float x4 = bf2f_lo(xv.z), x5 = bf2f_hi(xv.z);
    float x6 = bf2f_lo(xv.w), x7 = bf2f_hi(xv.w);
    float4 aA = *(const float4*)(att + off);
    float4 aB = *(const float4*)(att + off + 4);
    float a0 = 0.4f * aA.x, a1 = 0.4f * aA.y, a2 = 0.4f * aA.z, a3 = 0.4f * aA.w;
    float a4 = 0.4f * aB.x, a5 = 0.4f * aB.y, a6 = 0.4f * aB.z, a7 = 0.4f * aB.w;
    float srd = sr06[(size_t)d * 2 + h];
    float c0 = 0.f, c1 = 0.f, c2 = 0.f, c3 = 0.f;
    float c4 = 0.f, c5 = 0.f, c6 = 0.f, c7 = 0.f, den = 0.f;
    int beg = rowptr[d], endp = rowptr[d + 1];
    for (int base = beg - 1; base < endp; base += 4) {
        int jj = base + e;
        bool valid = (jj < endp);
        int s = (jj >= beg && valid) ? csr_src[jj] : d;   // jj==beg-1 => self loop
        uint4 lv = *(const uint4*)(xl + (size_t)s * 128 + off);
        float sls = sl06[(size_t)s * 2 + h];
        float l0 = bf2f_lo(lv.x), l1 = bf2f_hi(lv.x);
        float l2 = bf2f_lo(lv.y), l3 = bf2f_hi(lv.y);
        float l4 = bf2f_lo(lv.z), l5 = bf2f_hi(lv.z);
        float l6 = bf2f_lo(lv.w), l7 = bf2f_hi(lv.w);
        float v = a0 * fabsf(l0 + x0) + a1 * fabsf(l1 + x1)
                + a2 * fabsf(l2 + x2) + a3 * fabsf(l3 + x3)
                + a4 * fabsf(l4 + x4) + a5 * fabsf(l5 + x5)
                + a6 * fabsf(l6 + x6) + a7 * fabsf(l7 + x7);
        v += __shfl_xor(v, 1, 64); v += __shfl_xor(v, 2, 64); v += __shfl_xor(v, 4, 64);
        float p = valid ? __expf(sls + srd + v) : 0.f;
        c0 += p * l0; c1 += p * l1; c2 += p * l2; c3 += p * l3;
        c4 += p * l4; c5 += p * l5; c6 += p * l6; c7 += p * l7;
        den += p;
    }
    // fold the 4 edge slots (lane bits 4,5)
    c0 += __shfl_xor(c0, 16, 64); c1 += __shfl_xor(c1, 16, 64);
    c2 += __shfl_xor(c2, 16, 64); c3 += __shfl_xor(c3, 16, 64);
    c4 += __shfl_xor(c4, 16, 64); c5 += __shfl_xor(c5, 16, 64);
    c6 += __shfl_xor(c6, 16, 64); c7 += __shfl_xor(c7, 16, 64);
    den += __shfl_xor(den, 16, 64);
    c0 += __shfl_xor(c0, 32, 64); c1 += __shfl_xor(c1, 32, 64);
    c2 += __shfl_xor(c2, 32, 64); c3 += __shfl_xor(c3, 32, 64);
    c4 += __shfl_xor(c4, 32, 64); c5 += __shfl_xor(c5, 32, 64);
    c6 += __shfl_xor(c6, 32, 64); c7 += __shfl_xor(c7, 32, 64);
    den += __shfl_xor(den, 32, 64);
    if (e == 0) {
        float r = 1.f / den;
        const float* bv = bias + off;
        float o0 = c0 * r + bv[0], o1 = c1 * r + bv[1];
        float o2 = c2 * r + bv[2], o3 = c3 * r + bv[3];
        float o4 = c4 * r + bv[4], o5 = c5 * r + bv[5];
        float o6 = c6 * r + bv[6], o7 = c7 * r + bv[7];
        o0 = o0 > 0.f ? o0 : expm1f(o0);  o1 = o1 > 0.f ? o1 : expm1f(o1);
        o2 = o2 > 0.f ? o2 : expm1f(o2);  o3 = o3 > 0.f ? o3 : expm1f(o3);
        o4 = o4 > 0.f ? o4 : expm1f(o4);  o5 = o5 > 0.f ? o5 : expm1f(o5);
        o6 = o6 > 0.f ? o6 : expm1f(o6);  o7 = o7 > 0.f ? o7 : expm1f(o7);
        uint4 out;
        out.x = (unsigned)f2bf(o0) | ((unsigned)f2bf(o1) << 16);
        out.y = (unsigned)f2bf(o2) | ((unsigned)f2bf(o3) << 16);
        out.z = (unsigned)f2bf(o4) | ((unsigned)f2bf(o5) << 16);
        out.w = (unsigned)f2bf(o6) | ((unsigned)f2bf(o7) << 16);
        *(uint4*)(h1 + (size_t)d * 128 + off) = out;
    }
}

// ---------------- fused GATv2 layer 2: 8 edges/iter --------------------------
// lane = [e:3][g:3]; 8 lanes/edge, 8ch/lane.
__global__ void gat2_fused(const unsigned short* __restrict__ xl,
                           const unsigned short* __restrict__ xr,
                           const float* __restrict__ sl06, const float* __restrict__ sr06,
                           const float* __restrict__ att, const float* __restrict__ bias,
                           const int* __restrict__ rowptr, const int* __restrict__ csr_src,
                           float* __restrict__ h2, int n) {
    int d = (blockIdx.x * blockDim.x + threadIdx.x) >> 6;
    if (d >= n) return;
    int lane = threadIdx.x & 63;
    int e = lane >> 3;                  // edge slot 0..7
    int off = (lane & 7) * 8;           // 8-channel base
    uint4 xv = *(const uint4*)(xr + (size_t)d * 64 + off);
    float x0 = bf2f_lo(xv.x), x1 = bf2f_hi(xv.x);
    float x2 = bf2f_lo(xv.y), x3 = bf2f_hi(xv.y);
    float x4 = bf2f_lo(xv.z), x5 = bf2f_hi(xv.z);
    float x6 = bf2f_lo(xv.w), x7 = bf2f_hi(xv.w);
    float4 aA = *(const float4*)(att + off);
    float4 aB = *(const float4*)(att + off + 4);
    float a0 = 0.4f * aA.x, a1 = 0.4f * aA.y, a2 = 0.4f * aA.z, a3 = 0.4f * aA.w;
    float a4 = 0.4f * aB.x, a5 = 0.4f * aB.y, a6 = 0.4f * aB.z, a7 = 0.4f * aB.w;
    float srd = sr06[d];
    float c0 = 0.f, c1 = 0.f, c2 = 0.f, c3 = 0.f;
    float c4 = 0.f, c5 = 0.f, c6 = 0.f, c7 = 0.f, den = 0.f;
    int beg = rowptr[d], endp = rowptr[d + 1];
    for (int base = beg - 1; base < endp; base += 8) {
        int jj = base + e;
        bool valid = (jj < endp);
        int s = (jj >= beg && valid) ? csr_src[jj] : d;
        uint4 lv = *(const uint4*)(xl + (size_t)s * 64 + off);
        float sls = sl06[s];
        float l0 = bf2f_lo(lv.x), l1 = bf2f_hi(lv.x);
        float l2 = bf2f_lo(lv.y), l3 = bf2f_hi(lv.y);
        float l4 = bf2f_lo(lv.z), l5 = bf2f_hi(lv.z);
        float l6 = bf2f_lo(lv.w), l7 = bf2f_hi(lv.w);
        float v = a0 * fabsf(l0 + x0) + a1 * fabsf(l1 + x1)
                + a2 * fabsf(l2 + x2) + a3 * fabsf(l3 + x3)
                + a4 * fabsf(l4 + x4) + a5 * fabsf(l5 + x5)
                + a6 * fabsf(l6 + x6) + a7 * fabsf(l7 + x7);
        v += __shfl_xor(v, 1, 64); v += __shfl_xor(v, 2, 64); v += __shfl_xor(v, 4, 64);
        float p = valid ? __expf(sls + srd + v) : 0.f;
        c0 += p * l0; c1 += p * l1; c2 += p * l2; c3 += p * l3;
        c4 += p * l4; c5 += p * l5; c6 += p * l6; c7 += p * l7;
        den += p;
    }
    // fold the 8 edge slots (lane bits 3,4,5)
#pragma unroll
    for (int o = 8; o <= 32; o <<= 1) {
        c0 += __shfl_xor(c0, o, 64); c1 += __shfl_xor(c1, o, 64);
        c2 += __shfl_xor(c2, o, 64); c3 += __shfl_xor(c3, o, 64);
        c4 += __shfl_xor(c4, o, 64); c5 += __shfl_xor(c5, o, 64);
        c6 += __shfl_xor(c6, o, 64); c7 += __shfl_xor(c7, o, 64);
        den += __shfl_xor(den, o, 64);
    }
    if (e == 0) {
        float r = 1.f / den;
        const float* bv = bias + off;
        float o0 = c0 * r + bv[0], o1 = c1 * r + bv[1];
        float o2 = c2 * r + bv[2], o3 = c3 * r + bv[3];
        float o4 = c4 * r + bv[4], o5 = c5 * r + bv[5];
        float o6 = c6 * r + bv[6], o7 = c7 * r + bv[7];
        o0 = o0 > 0.f ? o0 : expm1f(o0);  o1 = o1 > 0.f ? o1 : expm1f(o1);
        o2 = o2 > 0.f ? o2 : expm1f(o2);  o3 = o3 > 0.f ? o3 : expm1f(o3);
        o4 = o4 > 0.f ? o4 : expm1f(o4);  o5 = o5 > 0.f ? o5 : expm1f(o5);
        o6 = o6 > 0.f ? o6 : expm1f(o6);  o7 = o7 > 0.f ? o7 : expm1f(o7);
        float4 A = {o0, o1, o2, o3}, B = {o4, o5, o6, o7};
        *(float4*)(h2 + (size_t)d * 64 + off)     = A;
        *(float4*)(h2 + (size_t)d * 64 + off + 4) = B;
    }
}

// mean-pool: batch sorted; run-length register accumulation per wave chunk.
__global__ void pool_rle(const float* __restrict__ h, const int* __restrict__ batch,
                         int n, int chunk, float* __restrict__ pooled,
                         float* __restrict__ counts) {
    int w = (blockIdx.x * blockDim.x + threadIdx.x) >> 6;
    int lane = threadIdx.x & 63;
    int start = w * chunk;
    int end = min(n, start + chunk);
    if (start >= end) return;
    int cur = batch[start];
    float acc = 0.f, cnt = 0.f;
    for (int node = start; node < end; node++) {
        int g = batch[node];
        if (g != cur) {
            atomicAdd(&pooled[(size_t)cur * 64 + lane], acc);
            if (lane == 0) atomicAdd(&counts[cur], cnt);
            acc = 0.f; cnt = 0.f; cur = g;
        }
        acc += h[(size_t)node * 64 + lane];
        cnt += 1.f;
    }
    atomicAdd(&pooled[(size_t)cur * 64 + lane], acc);
    if (lane == 0) atomicAdd(&counts[cur], cnt);
}

__global__ void head(const float* __restrict__ pooled, const float* __restrict__ counts,
                     const float* __restrict__ Wlin, const float* __restrict__ blin,
                     float* __restrict__ out, int NC) {
    int g = blockIdx.x;
    int lane = threadIdx.x;
    float cnt = fmaxf(counts[g], 1.f);
    float v = pooled[(size_t)g * 64 + lane] / cnt;
    for (int j = 0; j < NC; j++) {
        float t = v * Wlin[lane * NC + j];
        for (int off = 32; off > 0; off >>= 1) t += __shfl_down(t, off, 64);
        if (lane == 0) out[g * NC + j] = t + blin[j];
    }
}

extern "C" void kernel_launch(void* const* d_in, const int* in_sizes, int n_in,
                              void* d_out, int out_size, void* d_ws, size_t ws_size,
                              hipStream_t stream) {
    const float* x    = (const float*)d_in[0];
    const int*   ei   = (const int*)d_in[1];
    const int*   batch= (const int*)d_in[2];
    const float* Wl1  = (const float*)d_in[3];
    const float* Wr1  = (const float*)d_in[4];
    const float* att1 = (const float*)d_in[5];
    const float* b1   = (const float*)d_in[6];
    const float* Wl2  = (const float*)d_in[7];
    const float* Wr2  = (const float*)d_in[8];
    const float* att2 = (const float*)d_in[9];
    const float* b2   = (const float*)d_in[10];
    const float* Wlin = (const float*)d_in[11];
    const float* blin = (const float*)d_in[12];

    const int n    = in_sizes[0] / 128;   // 50000
    const int E    = in_sizes[1] / 2;     // 600000
    const int NC   = in_sizes[12];        // 10
    const int NG   = out_size / NC;       // 64

    const int* srcA = ei;
    const int* dstA = ei + E;

    // ---- workspace layout (bytes). Aliasing: xl2+xr2 fill xl1's region,
    //      h2 fills xr1's. h1 is kept live through gemm_dual<64>.
    uint8_t* w = (uint8_t*)d_ws;
    const size_t rowB = (size_t)n * 128 * 2;     // one N x 128 bf16 tensor
    unsigned short* xl1 = (unsigned short*)w;
    unsigned short* xr1 = (unsigned short*)(w + rowB);
    unsigned short* h1  = (unsigned short*)(w + 2 * rowB);
    unsigned short* xl2 = (unsigned short*)w;                       // n*64 bf16
    unsigned short* xr2 = (unsigned short*)(w + (size_t)n * 64 * 2);
    float*          h2  = (float*)(w + rowB);                       // n*64 fp32
    uint8_t* fx = w + 3 * rowB;
    unsigned short* Wl1p = (unsigned short*)fx;            fx += 16384 * 2;
    unsigned short* Wr1p = (unsigned short*)fx;            fx += 16384 * 2;
    unsigned short* Wl2p = (unsigned short*)fx;            fx += 8192 * 2;
    unsigned short* Wr2p = (unsigned short*)fx;            fx += 8192 * 2;
    float* sl1 = (float*)fx;                               fx += (size_t)n * 2 * 4;
    float* sr1 = (float*)fx;                               fx += (size_t)n * 2 * 4;
    float* sl2 = (float*)fx;                               fx += (size_t)n * 4;
    float* sr2 = (float*)fx;                               fx += (size_t)n * 4;
    float* pooled = (float*)fx;                            fx += (size_t)NG * 64 * 4;
    float* counts = (float*)fx;                            fx += (size_t)NG * 4;
    int* rowptr  = (int*)fx;                               fx += (size_t)(n + 1) * 4;
    int* deg     = (int*)fx;                               fx += (size_t)n * 4;
    int* cursor  = (int*)fx;                               fx += (size_t)n * 4;
    int* bsums   = (int*)fx;                               fx += 256 * 4;
    int* csr_src = (int*)fx;                               fx += (size_t)E * 4;
    if (ws_size < (size_t)(fx - (uint8_t*)d_ws)) return;   // bail visibly

    const int nb = (n + 255) / 256;

    // ---- weight packing + CSR build ----
    pack_weights<<<24, 256, 0, stream>>>(Wl1, Wr1, Wl2, Wr2, Wl1p, Wr1p, Wl2p, Wr2p);
    hipMemsetAsync(deg, 0, (size_t)n * sizeof(int), stream);
    hist_deg<<<(E + 255) / 256, 256, 0, stream>>>(dstA, E, deg);
    scan_block<<<nb, 256, 0, stream>>>(deg, n, rowptr, bsums);
    scan_sums<<<1, 256, 0, stream>>>(bsums, nb);
    scan_add<<<(n + 256) / 256, 256, 0, stream>>>(rowptr, cursor, bsums, n, E);
    csr_fill<<<(E + 255) / 256, 256, 0, stream>>>(srcA, dstA, E, cursor, csr_src);

    const int mblocks = (n + 63) / 64;       // MFMA gemm: 64 nodes/block
    const int dblocks = (n + 3) / 4;         // 4 dst-waves per 256-thread block

    // ---- layer 1 ----
    gemm_dual<128, false><<<mblocks, 256, 0, stream>>>(x, Wl1p, Wr1p, xl1, xr1, n);
    node_dot<128, 2><<<dblocks, 256, 0, stream>>>(xl1, xr1, att1, sl1, sr1, n);
    gat1_fused<<<dblocks, 256, 0, stream>>>(xl1, xr1, sl1, sr1, att1, b1,
                                            rowptr, csr_src, h1, n);

    // ---- layer 2 ----
    gemm_dual<64, true><<<mblocks, 256, 0, stream>>>(h1, Wl2p, Wr2p, xl2, xr2, n);
    node_dot<64, 1><<<dblocks, 256, 0, stream>>>(xl2, xr2, att2, sl2, sr2, n);
    gat2_fused<<<dblocks, 256, 0, stream>>>(xl2, xr2, sl2, sr2, att2, b2,
                                            rowptr, csr_src, h2, n);

    // ---- pool + head ----
    hipMemsetAsync(pooled, 0, (size_t)(NG * 64 + NG) * sizeof(float), stream);
    {
        const int nwaves = 1024;
        const int chunk = (n + nwaves - 1) / nwaves;
        pool_rle<<<256, 256, 0, stream>>>(h2, batch, n, chunk, pooled, counts);
    }
    head<<<NG, 64, 0, stream>>>(pooled, counts, Wlin, blin, (float*)d_out, NC);
}

// Round 7
// 319.572 us; speedup vs baseline: 1.0282x; 1.0282x over previous
//
#include <hip/hip_runtime.h>
#include <hip/hip_fp16.h>
#include <cstdint>
#include <cstddef>

// ---------------------------------------------------------------------------
// GATv2Classifier: x(N,128) -> GATv2(2 heads,64,concat) -> elu
//                 -> GATv2(1 head,64) -> elu -> mean-pool(64 graphs) -> linear(10)
// R1: pool rle (batch sorted). 1368->999us.
// R2: CSR gather + single-pass fused softmax-agg. 999->567us.
// R3: bf16 + MFMA GEMMs. 567->405us.
// R4: edge-parallel waves. 405->328us.
// R5: leaky(t)=0.6t+0.4|t| precompute + 4/8 edges/iter. NEUTRAL (328us):
//     gat VALUBusy rose to 80% -- per-CHANNEL VALU is the pipe consumer.
// R6: fp16 storage + packed-fp16 score (__hadd2/and/__hfma2: 3 VALU per 2ch
//     vs 6), agg via half->float fma (v_fma_mix candidate); node_dot fused
//     into gemm_dual epilogue (2 kernels + 38MB re-read removed).
// ---------------------------------------------------------------------------

typedef __attribute__((ext_vector_type(8))) short s8v;   // 8 bf16 (4 VGPRs)
typedef __attribute__((ext_vector_type(4))) float f4v;   // MFMA accumulator

__device__ __forceinline__ unsigned short f2bf(float f) {
    unsigned u = __float_as_uint(f);
    unsigned r = (u + 0x7fffu + ((u >> 16) & 1u)) >> 16;   // RNE
    return (unsigned short)r;
}
__device__ __forceinline__ __half2 habs2_(__half2 x) {
    unsigned u; __builtin_memcpy(&u, &x, 4);
    u &= 0x7fff7fffu;
    __half2 r; __builtin_memcpy(&r, &u, 4);
    return r;
}
union U4H { uint4 u; __half2 h[4]; };

// ---------------- weight packing to MFMA B-fragment layout ----------------
// B-frag 16x16x32: lane holds B[k = ks*32 + (lane>>4)*8 + j][col = ct*16 + (lane&15)]
__global__ void pack_weights(const float* __restrict__ Wl1, const float* __restrict__ Wr1,
                             const float* __restrict__ Wl2, const float* __restrict__ Wr2,
                             unsigned short* __restrict__ Wl1p, unsigned short* __restrict__ Wr1p,
                             unsigned short* __restrict__ Wl2p, unsigned short* __restrict__ Wr2p) {
    int t = blockIdx.x * blockDim.x + threadIdx.x;
    const float* W; unsigned short* Wp; int CO, base;
    if      (t < 2048) { W = Wl1; Wp = Wl1p; CO = 128; base = t; }
    else if (t < 4096) { W = Wr1; Wp = Wr1p; CO = 128; base = t - 2048; }
    else if (t < 5120) { W = Wl2; Wp = Wl2p; CO = 64;  base = t - 4096; }
    else if (t < 6144) { W = Wr2; Wp = Wr2p; CO = 64;  base = t - 5120; }
    else return;
    int lane = base & 63, ks = (base >> 6) & 3, ct = base >> 8;
    int col = ct * 16 + (lane & 15);
    int k0 = ks * 32 + (lane >> 4) * 8;
    unsigned short u[8];
#pragma unroll
    for (int j = 0; j < 8; j++) u[j] = f2bf(W[(size_t)(k0 + j) * CO + col]);
    unsigned* dst = (unsigned*)(Wp + (size_t)base * 8);
    dst[0] = u[0] | ((unsigned)u[1] << 16);
    dst[1] = u[2] | ((unsigned)u[3] << 16);
    dst[2] = u[4] | ((unsigned)u[5] << 16);
    dst[3] = u[6] | ((unsigned)u[7] << 16);
}

// ---- dual MFMA GEMM: outL/outR (fp16) = A@Wl / A@Wr, + fused att-dot ------
// Epilogue also computes sl06[node(,h)] = 0.6*(att_h . outL_row) and sr06
// likewise, from the fp32 accumulators (replaces the node_dot kernels).
template<int CO, bool A_BF16>
__global__ void gemm_dual(const void* __restrict__ Aptr,
                          const unsigned short* __restrict__ Wlp,
                          const unsigned short* __restrict__ Wrp,
                          __half* __restrict__ outL, __half* __restrict__ outR,
                          const float* __restrict__ att,
                          float* __restrict__ sl06, float* __restrict__ sr06, int n) {
    constexpr int NT = CO / 16;
    constexpr int H  = CO / 64;          // heads (2 for layer1, 1 for layer2)
    int lane = threadIdx.x & 63;
    int node0 = blockIdx.x * 64 + (threadIdx.x >> 6) * 16;
    int m = lane & 15, quad = lane >> 4;
    int row = node0 + m;
    s8v a[4];
    if (A_BF16) {
        const unsigned short* A = (const unsigned short*)Aptr;
#pragma unroll
        for (int ks = 0; ks < 4; ks++) {
            if (row < n) a[ks] = *(const s8v*)(A + (size_t)row * 128 + ks * 32 + quad * 8);
            else { union { s8v v; unsigned short u[8]; } z;
#pragma unroll
                   for (int j = 0; j < 8; j++) z.u[j] = 0; a[ks] = z.v; }
        }
    } else {
        const float* A = (const float*)Aptr;
#pragma unroll
        for (int ks = 0; ks < 4; ks++) {
            union { s8v v; unsigned short u[8]; } t;
#pragma unroll
            for (int j = 0; j < 8; j++)
                t.u[j] = (row < n) ? f2bf(A[(size_t)row * 128 + ks * 32 + quad * 8 + j]) : 0;
            a[ks] = t.v;
        }
    }
    int r0 = quad * 4;
    float pl[2][4] = {{0.f,0.f,0.f,0.f},{0.f,0.f,0.f,0.f}};
    float pr[2][4] = {{0.f,0.f,0.f,0.f},{0.f,0.f,0.f,0.f}};
#pragma unroll
    for (int ct = 0; ct < NT; ct++) {
        f4v cl = {0.f, 0.f, 0.f, 0.f}, cr = {0.f, 0.f, 0.f, 0.f};
#pragma unroll
        for (int ks = 0; ks < 4; ks++) {
            s8v bl = *(const s8v*)(Wlp + ((size_t)(ct * 4 + ks) * 64 + lane) * 8);
            s8v br = *(const s8v*)(Wrp + ((size_t)(ct * 4 + ks) * 64 + lane) * 8);
            cl = __builtin_amdgcn_mfma_f32_16x16x32_bf16(a[ks], bl, cl, 0, 0, 0);
            cr = __builtin_amdgcn_mfma_f32_16x16x32_bf16(a[ks], br, cr, 0, 0, 0);
        }
        int col = ct * 16 + m;           // C/D: col=lane&15, row=(lane>>4)*4+reg
        float am = att[col];
#pragma unroll
        for (int r = 0; r < 4; r++) {
            int nd = node0 + r0 + r;
            pl[ct >> 2][r] = fmaf(am, cl[r], pl[ct >> 2][r]);
            pr[ct >> 2][r] = fmaf(am, cr[r], pr[ct >> 2][r]);
            if (nd < n) {
                outL[(size_t)nd * CO + col] = __float2half(cl[r]);
                outR[(size_t)nd * CO + col] = __float2half(cr[r]);
            }
        }
    }
    // reduce dot partials across the 16 m-lanes of each quad, write per node
#pragma unroll
    for (int h = 0; h < H; h++) {
#pragma unroll
        for (int r = 0; r < 4; r++) {
            float vl = pl[h][r], vr = pr[h][r];
#pragma unroll
            for (int o = 1; o < 16; o <<= 1) {
                vl += __shfl_xor(vl, o, 64); vr += __shfl_xor(vr, o, 64);
            }
            if (m == 0) {
                int nd = node0 + r0 + r;
                if (nd < n) {
                    if (H == 2) {
                        sl06[(size_t)nd * 2 + h] = 0.6f * vl;
                        sr06[(size_t)nd * 2 + h] = 0.6f * vr;
                    } else {
                        sl06[nd] = 0.6f * vl;
                        sr06[nd] = 0.6f * vr;
                    }
                }
            }
        }
    }
}

// ---------------- CSR build ----------------
__global__ void hist_deg(const int* __restrict__ dstA, int E, int* __restrict__ deg) {
    int i = blockIdx.x * blockDim.x + threadIdx.x;
    if (i < E) atomicAdd(&deg[dstA[i]], 1);
}

__global__ void scan_block(const int* __restrict__ deg, int n,
                           int* __restrict__ rowptr, int* __restrict__ bsums) {
    __shared__ int tmp[256];
    int i = blockIdx.x * 256 + threadIdx.x;
    int v = (i < n) ? deg[i] : 0;
    tmp[threadIdx.x] = v;
    __syncthreads();
    for (int off = 1; off < 256; off <<= 1) {
        int t = (threadIdx.x >= (unsigned)off) ? tmp[threadIdx.x - off] : 0;
        __syncthreads();
        tmp[threadIdx.x] += t;
        __syncthreads();
    }
    if (i < n) rowptr[i] = tmp[threadIdx.x] - v;           // exclusive
    if (threadIdx.x == 255) bsums[blockIdx.x] = tmp[255];
}

__global__ void scan_sums(int* __restrict__ bsums, int nb) {
    __shared__ int tmp[256];
    int v = (threadIdx.x < (unsigned)nb) ? bsums[threadIdx.x] : 0;
    tmp[threadIdx.x] = v;
    __syncthreads();
    for (int off = 1; off < 256; off <<= 1) {
        int t = (threadIdx.x >= (unsigned)off) ? tmp[threadIdx.x - off] : 0;
        __syncthreads();
        tmp[threadIdx.x] += t;
        __syncthreads();
    }
    if (threadIdx.x < (unsigned)nb) bsums[threadIdx.x] = tmp[threadIdx.x] - v;
}

__global__ void scan_add(int* __restrict__ rowptr, int* __restrict__ cursor,
                         const int* __restrict__ bsums, int n, int E) {
    int i = blockIdx.x * 256 + threadIdx.x;
    if (i < n) {
        int v = rowptr[i] + bsums[i >> 8];
        rowptr[i] = v;
        cursor[i] = v;
    }
    if (i == n) rowptr[n] = E;
}

__global__ void csr_fill(const int* __restrict__ srcA, const int* __restrict__ dstA,
                         int E, int* __restrict__ cursor, int* __restrict__ csr_src) {
    int i = blockIdx.x * blockDim.x + threadIdx.x;
    if (i < E) {
        int pos = atomicAdd(&cursor[dstA[i]], 1);
        csr_src[pos] = srcA[i];
    }
}

// ---------------- fused GATv2 layer 1: 4 edges/iter, packed fp16 score ------
// lane = [e:2][h:1][g:3]; 16 lanes/edge (2 heads x 8 lanes x 8ch dwordx4).
// e = sl06[s,h] + sr06[d,h] + sum_c (0.4 a_c)|xl_c + xr_c|  (packed fp16).
__global__ void gat1_fused(const __half* __restrict__ xl, const __half* __restrict__ xr,
                           const float* __restrict__ sl06, const float* __restrict__ sr06,
                           const float* __restrict__ att, const float* __restrict__ bias,
                           const int* __restrict__ rowptr, const int* __restrict__ csr_src,
                           unsigned short* __restrict__ h1, int n) {
    int d = (blockIdx.x * blockDim.x + threadIdx.x) >> 6;
    if (d >= n) return;
    int lane = threadIdx.x & 63;
    int e = lane >> 4;                  // edge slot 0..3
    int h = (lane >> 3) & 1;            // head
    int off = h * 64 + (lane & 7) * 8;  // 8-channel base
    U4H xv; xv.u = *(const uint4*)(xr + (size_t)d * 128 + off);
    float4 aA = *(const float4*)(att + off);
    float4 aB = *(const float4*)(att + off + 4);
    __half2 a2[4];
    a2[0] = __floats2half2_rn(0.4f * aA.x, 0.4f * aA.y);
    a2[1] = __floats2half2_rn(0.4f * aA.z, 0.4f * aA.w);
    a2[2] = __floats2half2_rn(0.4f * aB.x, 0.4f * aB.y);
    a2[3] = __floats2half2_rn(0.4f * aB.z, 0.4f * aB.w);
    float srd = sr06[(size_t)d * 2 + h];
    float c0 = 0.f, c1 = 0.f, c2 = 0.f, c3 = 0.f;
    float c4 = 0.f, c5 = 0.f, c6 = 0.f, c7 = 0.f, den = 0.f;
    int beg = rowptr[d], endp = rowptr[d + 1];
    for (int base = beg - 1; base < endp; base += 4) {
        int jj = base + e;
        bool valid = (jj < endp);
        int s = (jj >= beg && valid) ? csr_src[jj] : d;   // jj==beg-1 => self loop
        U4H lv; lv.u = *(const uint4*)(xl + (size_t)s * 128 + off);
        float sls = sl06[(size_t)s * 2 + h];
        __half2 sc = __floats2half2_rn(0.f, 0.f);
        sc = __hfma2(a2[0], habs2_(__hadd2(lv.h[0], xv.h[0])), sc);
        sc = __hfma2(a2[1], habs2_(__hadd2(lv.h[1], xv.h[1])), sc);
        sc = __hfma2(a2[2], habs2_(__hadd2(lv.h[2], xv.h[2])), sc);
        sc = __hfma2(a2[3], habs2_(__hadd2(lv.h[3], xv.h[3])), sc);
        float v = __low2float(sc) + __high2float(sc);
        v += __shfl_xor(v, 1, 64); v += __shfl_xor(v, 2, 64); v += __shfl_xor(v, 4, 64);
        float p = valid ? __expf(sls + srd + v) : 0.f;
        c0 = fmaf(__low2float(lv.h[0]),  p, c0);
        c1 = fmaf(__high2float(lv.h[0]), p, c1);
        c2 = fmaf(__low2float(lv.h[1]),  p, c2);
        c3 = fmaf(__high2float(lv.h[1]), p, c3);
        c4 = fmaf(__low2float(lv.h[2]),  p, c4);
        c5 = fmaf(__high2float(lv.h[2]), p, c5);
        c6 = fmaf(__low2float(lv.h[3]),  p, c6);
        c7 = fmaf(__high2float(lv.h[3]), p, c7);
        den += p;
    }
    // fold the 4 edge slots (lane bits 4,5)
#pragma unroll
    for (int o = 16; o <= 32; o <<= 1) {
        c0 += __shfl_xor(c0, o, 64); c1 += __shfl_xor(c1, o, 64);
        c2 += __shfl_xor(c2, o, 64); c3 += __shfl_xor(c3, o, 64);
        c4 += __shfl_xor(c4, o, 64); c5 += __shfl_xor(c5, o, 64);
        c6 += __shfl_xor(c6, o, 64); c7 += __shfl_xor(c7, o, 64);
        den += __shfl_xor(den, o, 64);
    }
    if (e == 0) {
        float r = 1.f / den;
        const float* bv = bias + off;
        float o0 = c0 * r + bv[0], o1 = c1 * r + bv[1];
        float o2 = c2 * r + bv[2], o3 = c3 * r + bv[3];
        float o4 = c4 * r + bv[4], o5 = c5 * r + bv[5];
        float o6 = c6 * r + bv[6], o7 = c7 * r + bv[7];
        o0 = o0 > 0.f ? o0 : expm1f(o0);  o1 = o1 > 0.f ? o1 : expm1f(o1);
        o2 = o2 > 0.f ? o2 : expm1f(o2);  o3 = o3 > 0.f ? o3 : expm1f(o3);
        o4 = o4 > 0.f ? o4 : expm1f(o4);  o5 = o5 > 0.f ? o5 : expm1f(o5);
        o6 = o6 > 0.f ? o6 : expm1f(o6);  o7 = o7 > 0.f ? o7 : expm1f(o7);
        uint4 out;
        out.x = (unsigned)f2bf(o0) | ((unsigned)f2bf(o1) << 16);
        out.y = (unsigned)f2bf(o2) | ((unsigned)f2bf(o3) << 16);
        out.z = (unsigned)f2bf(o4) | ((unsigned)f2bf(o5) << 16);
        out.w = (unsigned)f2bf(o6) | ((unsigned)f2bf(o7) << 16);
        *(uint4*)(h1 + (size_t)d * 128 + off) = out;
    }
}

// ---------------- fused GATv2 layer 2: 8 edges/iter, packed fp16 score ------
// lane = [e:3][g:3]; 8 lanes/edge, 8ch/lane.
__global__ void gat2_fused(const __half* __restrict__ xl, const __half* __restrict__ xr,
                           const float* __restrict__ sl06, const float* __restrict__ sr06,
                           const float* __restrict__ att, const float* __restrict__ bias,
                           const int* __restrict__ rowptr, const int* __restrict__ csr_src,
                           float* __restrict__ h2, int n) {
    int d = (blockIdx.x * blockDim.x + threadIdx.x) >> 6;
    if (d >= n) return;
    int lane = threadIdx.x & 63;
    int e = lane >> 3;                  // edge slot 0..7
    int off = (lane & 7) * 8;           // 8-channel base
    U4H xv; xv.u = *(const uint4*)(xr + (size_t)d * 64 + off);
    float4 aA = *(const float4*)(att + off);
    float4 aB = *(const float4*)(att + off + 4);
    __half2 a2[4];
    a2[0] = __floats2half2_rn(0.4f * aA.x, 0.4f * aA.y);
    a2[1] = __floats2half2_rn(0.4f * aA.z, 0.4f * aA.w);
    a2[2] = __floats2half2_rn(0.4f * aB.x, 0.4f * aB.y);
    a2[3] = __floats2half2_rn(0.4f * aB.z, 0.4f * aB.w);
    float srd = sr06[d];
    float c0 = 0.f, c1 = 0.f, c2 = 0.f, c3 = 0.f;
    float c4 = 0.f, c5 = 0.f, c6 = 0.f, c7 = 0.f, den = 0.f;
    int beg = rowptr[d], endp = rowptr[d + 1];
    for (int base = beg - 1; base < endp; base += 8) {
        int jj = base + e;
        bool valid = (jj < endp);
        int s = (jj >= beg && valid) ? csr_src[jj] : d;
        U4H lv; lv.u = *(const uint4*)(xl + (size_t)s * 64 + off);
        float sls = sl06[s];
        __half2 sc = __floats2half2_rn(0.f, 0.f);
        sc = __hfma2(a2[0], habs2_(__hadd2(lv.h[0], xv.h[0])), sc);
        sc = __hfma2(a2[1], habs2_(__hadd2(lv.h[1], xv.h[1])), sc);
        sc = __hfma2(a2[2], habs2_(__hadd2(lv.h[2], xv.h[2])), sc);
        sc = __hfma2(a2[3], habs2_(__hadd2(lv.h[3], xv.h[3])), sc);
        float v = __low2float(sc) + __high2float(sc);
        v += __shfl_xor(v, 1, 64); v += __shfl_xor(v, 2, 64); v += __shfl_xor(v, 4, 64);
        float p = valid ? __expf(sls + srd + v) : 0.f;
        c0 = fmaf(__low2float(lv.h[0]),  p, c0);
        c1 = fmaf(__high2float(lv.h[0]), p, c1);
        c2 = fmaf(__low2float(lv.h[1]),  p, c2);
        c3 = fmaf(__high2float(lv.h[1]), p, c3);
        c4 = fmaf(__low2float(lv.h[2]),  p, c4);
        c5 = fmaf(__high2float(lv.h[2]), p, c5);
        c6 = fmaf(__low2float(lv.h[3]),  p, c6);
        c7 = fmaf(__high2float(lv.h[3]), p, c7);
        den += p;
    }
    // fold the 8 edge slots (lane bits 3,4,5)
#pragma unroll
    for (int o = 8; o <= 32; o <<= 1) {
        c0 += __shfl_xor(c0, o, 64); c1 += __shfl_xor(c1, o, 64);
        c2 += __shfl_xor(c2, o, 64); c3 += __shfl_xor(c3, o, 64);
        c4 += __shfl_xor(c4, o, 64); c5 += __shfl_xor(c5, o, 64);
        c6 += __shfl_xor(c6, o, 64); c7 += __shfl_xor(c7, o, 64);
        den += __shfl_xor(den, o, 64);
    }
    if (e == 0) {
        float r = 1.f / den;
        const float* bv = bias + off;
        float o0 = c0 * r + bv[0], o1 = c1 * r + bv[1];
        float o2 = c2 * r + bv[2], o3 = c3 * r + bv[3];
        float o4 = c4 * r + bv[4], o5 = c5 * r + bv[5];
        float o6 = c6 * r + bv[6], o7 = c7 * r + bv[7];
        o0 = o0 > 0.f ? o0 : expm1f(o0);  o1 = o1 > 0.f ? o1 : expm1f(o1);
        o2 = o2 > 0.f ? o2 : expm1f(o2);  o3 = o3 > 0.f ? o3 : expm1f(o3);
        o4 = o4 > 0.f ? o4 : expm1f(o4);  o5 = o5 > 0.f ? o5 : expm1f(o5);
        o6 = o6 > 0.f ? o6 : expm1f(o6);  o7 = o7 > 0.f ? o7 : expm1f(o7);
        float4 A = {o0, o1, o2, o3}, B = {o4, o5, o6, o7};
        *(float4*)(h2 + (size_t)d * 64 + off)     = A;
        *(float4*)(h2 + (size_t)d * 64 + off + 4) = B;
    }
}

// mean-pool: batch sorted; run-length register accumulation per wave chunk.
__global__ void pool_rle(const float* __restrict__ h, const int* __restrict__ batch,
                         int n, int chunk, float* __restrict__ pooled,
                         float* __restrict__ counts) {
    int w = (blockIdx.x * blockDim.x + threadIdx.x) >> 6;
    int lane = threadIdx.x & 63;
    int start = w * chunk;
    int end = min(n, start + chunk);
    if (start >= end) return;
    int cur = batch[start];
    float acc = 0.f, cnt = 0.f;
    for (int node = start; node < end; node++) {
        int g = batch[node];
        if (g != cur) {
            atomicAdd(&pooled[(size_t)cur * 64 + lane], acc);
            if (lane == 0) atomicAdd(&counts[cur], cnt);
            acc = 0.f; cnt = 0.f; cur = g;
        }
        acc += h[(size_t)node * 64 + lane];
        cnt += 1.f;
    }
    atomicAdd(&pooled[(size_t)cur * 64 + lane], acc);
    if (lane == 0) atomicAdd(&counts[cur], cnt);
}

__global__ void head(const float* __restrict__ pooled, const float* __restrict__ counts,
                     const float* __restrict__ Wlin, const float* __restrict__ blin,
                     float* __restrict__ out, int NC) {
    int g = blockIdx.x;
    int lane = threadIdx.x;
    float cnt = fmaxf(counts[g], 1.f);
    float v = pooled[(size_t)g * 64 + lane] / cnt;
    for (int j = 0; j < NC; j++) {
        float t = v * Wlin[lane * NC + j];
        for (int off = 32; off > 0; off >>= 1) t += __shfl_down(t, off, 64);
        if (lane == 0) out[g * NC + j] = t + blin[j];
    }
}

extern "C" void kernel_launch(void* const* d_in, const int* in_sizes, int n_in,
                              void* d_out, int out_size, void* d_ws, size_t ws_size,
                              hipStream_t stream) {
    const float* x    = (const float*)d_in[0];
    const int*   ei   = (const int*)d_in[1];
    const int*   batch= (const int*)d_in[2];
    const float* Wl1  = (const float*)d_in[3];
    const float* Wr1  = (const float*)d_in[4];
    const float* att1 = (const float*)d_in[5];
    const float* b1   = (const float*)d_in[6];
    const float* Wl2  = (const float*)d_in[7];
    const float* Wr2  = (const float*)d_in[8];
    const float* att2 = (const float*)d_in[9];
    const float* b2   = (const float*)d_in[10];
    const float* Wlin = (const float*)d_in[11];
    const float* blin = (const float*)d_in[12];

    const int n    = in_sizes[0] / 128;   // 50000
    const int E    = in_sizes[1] / 2;     // 600000
    const int NC   = in_sizes[12];        // 10
    const int NG   = out_size / NC;       // 64

    const int* srcA = ei;
    const int* dstA = ei + E;

    // ---- workspace layout (bytes). Aliasing: xl2+xr2 fill xl1's region,
    //      h2 fills xr1's. h1 (bf16) is kept live through gemm_dual<64>.
    uint8_t* w = (uint8_t*)d_ws;
    const size_t rowB = (size_t)n * 128 * 2;     // one N x 128 16-bit tensor
    __half*         xl1 = (__half*)w;
    __half*         xr1 = (__half*)(w + rowB);
    unsigned short* h1  = (unsigned short*)(w + 2 * rowB);
    __half*         xl2 = (__half*)w;                           // n*64 fp16
    __half*         xr2 = (__half*)(w + (size_t)n * 64 * 2);
    float*          h2  = (float*)(w + rowB);                   // n*64 fp32
    uint8_t* fx = w + 3 * rowB;
    unsigned short* Wl1p = (unsigned short*)fx;            fx += 16384 * 2;
    unsigned short* Wr1p = (unsigned short*)fx;            fx += 16384 * 2;
    unsigned short* Wl2p = (unsigned short*)fx;            fx += 8192 * 2;
    unsigned short* Wr2p = (unsigned short*)fx;            fx += 8192 * 2;
    float* sl1 = (float*)fx;                               fx += (size_t)n * 2 * 4;
    float* sr1 = (float*)fx;                               fx += (size_t)n * 2 * 4;
    float* sl2 = (float*)fx;                               fx += (size_t)n * 4;
    float* sr2 = (float*)fx;                               fx += (size_t)n * 4;
    float* pooled = (float*)fx;                            fx += (size_t)NG * 64 * 4;
    float* counts = (float*)fx;                            fx += (size_t)NG * 4;
    int* rowptr  = (int*)fx;                               fx += (size_t)(n + 1) * 4;
    int* deg     = (int*)fx;                               fx += (size_t)n * 4;
    int* cursor  = (int*)fx;                               fx += (size_t)n * 4;
    int* bsums   = (int*)fx;                               fx += 256 * 4;
    int* csr_src = (int*)fx;                               fx += (size_t)E * 4;
    if (ws_size < (size_t)(fx - (uint8_t*)d_ws)) return;   // bail visibly

    const int nb = (n + 255) / 256;

    // ---- weight packing + CSR build ----
    pack_weights<<<24, 256, 0, stream>>>(Wl1, Wr1, Wl2, Wr2, Wl1p, Wr1p, Wl2p, Wr2p);
    hipMemsetAsync(deg, 0, (size_t)n * sizeof(int), stream);
    hist_deg<<<(E + 255) / 256, 256, 0, stream>>>(dstA, E, deg);
    scan_block<<<nb, 256, 0, stream>>>(deg, n, rowptr, bsums);
    scan_sums<<<1, 256, 0, stream>>>(bsums, nb);
    scan_add<<<(n + 256) / 256, 256, 0, stream>>>(rowptr, cursor, bsums, n, E);
    csr_fill<<<(E + 255) / 256, 256, 0, stream>>>(srcA, dstA, E, cursor, csr_src);

    const int mblocks = (n + 63) / 64;       // MFMA gemm: 64 nodes/block
    const int dblocks = (n + 3) / 4;         // 4 dst-waves per 256-thread block

    // ---- layer 1 ----
    gemm_dual<128, false><<<mblocks, 256, 0, stream>>>(x, Wl1p, Wr1p, xl1, xr1,
                                                       att1, sl1, sr1, n);
    gat1_fused<<<dblocks, 256, 0, stream>>>(xl1, xr1, sl1, sr1, att1, b1,
                                            rowptr, csr_src, h1, n);

    // ---- layer 2 ----
    gemm_dual<64, true><<<mblocks, 256, 0, stream>>>(h1, Wl2p, Wr2p, xl2, xr2,
                                                     att2, sl2, sr2, n);
    gat2_fused<<<dblocks, 256, 0, stream>>>(xl2, xr2, sl2, sr2, att2, b2,
                                            rowptr, csr_src, h2, n);

    // ---- pool + head ----
    hipMemsetAsync(pooled, 0, (size_t)(NG * 64 + NG) * sizeof(float), stream);
    {
        const int nwaves = 1024;
        const int chunk = (n + nwaves - 1) / nwaves;
        pool_rle<<<256, 256, 0, stream>>>(h2, batch, n, chunk, pooled, counts);
    }
    head<<<NG, 64, 0, stream>>>(pooled, counts, Wlin, blin, (float*)d_out, NC);
}

// Round 8
// 299.353 us; speedup vs baseline: 1.0976x; 1.0675x over previous
//
#include <hip/hip_runtime.h>
#include <hip/hip_fp16.h>
#include <cstdint>
#include <cstddef>

// ---------------------------------------------------------------------------
// GATv2Classifier: x(N,128) -> GATv2(2 heads,64,concat) -> elu
//                 -> GATv2(1 head,64) -> elu -> mean-pool(64 graphs) -> linear(10)
// R1: pool rle (batch sorted). 1368->999us.
// R2: CSR gather + single-pass fused softmax-agg. 999->567us.
// R3: bf16 + MFMA GEMMs. 567->405us.
// R4: edge-parallel waves. 405->328us.
// R5: leaky = 0.6t+0.4|t| precompute. NEUTRAL.
// R6: fp16 storage + packed-fp16 score. 328->320us. Counter arithmetic says
//     ~70 wave-instr/edge; loop body needs ~15 -> per-dst overhead dominates
//     (expm1f epilogue, folds, 64-bit addressing, per-dst setup).
// R7: (a) bias+ELU deferred out of gat kernels (into gemm<64> node-frag load
//     and pool prologue); (b) exp->exp2 with log2e folded into sl06/a2
//     constants; (c) 32-bit gather addressing; (d) gemm MFMA operand swap ->
//     transposed D: contiguous out-channels per lane -> dwordx2 stores
//     (16/lane vs 64x 2B) and tiny att-dot fold.
// ---------------------------------------------------------------------------

typedef __attribute__((ext_vector_type(8))) short s8v;   // 8 bf16 (4 VGPRs)
typedef __attribute__((ext_vector_type(4))) float f4v;   // MFMA accumulator

#define LOG2E 1.44269504f

__device__ __forceinline__ unsigned short f2bf(float f) {
    unsigned u = __float_as_uint(f);
    unsigned r = (u + 0x7fffu + ((u >> 16) & 1u)) >> 16;   // RNE
    return (unsigned short)r;
}
__device__ __forceinline__ __half2 habs2_(__half2 x) {
    unsigned u; __builtin_memcpy(&u, &x, 4);
    u &= 0x7fff7fffu;
    __half2 r; __builtin_memcpy(&r, &u, 4);
    return r;
}
__device__ __forceinline__ float elu_(float v) {          // exp-based ELU
    return v > 0.f ? v : exp2f(v * LOG2E) - 1.f;
}
union U4H { uint4 u; __half2 h[4]; };

// ---------------- weight packing to MFMA fragment layout --------------------
// Fragment (A or B, layouts are lane-symmetric): lane holds
// W[k = ks*32 + (lane>>4)*8 + j][col = ct*16 + (lane&15)], j=0..7 contiguous.
__global__ void pack_weights(const float* __restrict__ Wl1, const float* __restrict__ Wr1,
                             const float* __restrict__ Wl2, const float* __restrict__ Wr2,
                             unsigned short* __restrict__ Wl1p, unsigned short* __restrict__ Wr1p,
                             unsigned short* __restrict__ Wl2p, unsigned short* __restrict__ Wr2p) {
    int t = blockIdx.x * blockDim.x + threadIdx.x;
    const float* W; unsigned short* Wp; int CO, base;
    if      (t < 2048) { W = Wl1; Wp = Wl1p; CO = 128; base = t; }
    else if (t < 4096) { W = Wr1; Wp = Wr1p; CO = 128; base = t - 2048; }
    else if (t < 5120) { W = Wl2; Wp = Wl2p; CO = 64;  base = t - 4096; }
    else if (t < 6144) { W = Wr2; Wp = Wr2p; CO = 64;  base = t - 5120; }
    else return;
    int lane = base & 63, ks = (base >> 6) & 3, ct = base >> 8;
    int col = ct * 16 + (lane & 15);
    int k0 = ks * 32 + (lane >> 4) * 8;
    unsigned short u[8];
#pragma unroll
    for (int j = 0; j < 8; j++) u[j] = f2bf(W[(size_t)(k0 + j) * CO + col]);
    unsigned* dst = (unsigned*)(Wp + (size_t)base * 8);
    dst[0] = u[0] | ((unsigned)u[1] << 16);
    dst[1] = u[2] | ((unsigned)u[3] << 16);
    dst[2] = u[4] | ((unsigned)u[5] << 16);
    dst[3] = u[6] | ((unsigned)u[7] << 16);
}

// ---- dual MFMA GEMM (transposed): mfma(Wfrag, Xfrag) => D[row=outch][col=node]
// Lane owns node = node0w + (lane&15); regs = 4 consecutive out-channels
// (ct*16 + quad*4 + r) -> packed dwordx2 fp16 stores. Epilogue also emits
// sl06/sr06 = 0.6*log2e*(att_h . row) from the fp32 accumulators.
// ELU_A: node input is raw bf16 h1; apply elu(x + bias_in[k]) while loading.
template<int CO, bool ELU_A>
__global__ void gemm_dual(const void* __restrict__ Aptr,
                          const unsigned short* __restrict__ Wlp,
                          const unsigned short* __restrict__ Wrp,
                          __half* __restrict__ outL, __half* __restrict__ outR,
                          const float* __restrict__ att, const float* __restrict__ bias_in,
                          float* __restrict__ sl06, float* __restrict__ sr06, int n) {
    constexpr int NT = CO / 16;
    constexpr int H  = CO / 64;          // heads (2 layer1, 1 layer2)
    int lane = threadIdx.x & 63;
    int node0 = blockIdx.x * 64 + (threadIdx.x >> 6) * 16;
    int m = lane & 15, quad = lane >> 4;
    int row = node0 + m;                 // node this lane loads AND owns in D
    s8v a[4];
#pragma unroll
    for (int ks = 0; ks < 4; ks++) {
        union { s8v v; unsigned short u[8]; } t;
        int k0 = ks * 32 + quad * 8;
        if (row < n) {
            if (ELU_A) {
                const unsigned short* A = (const unsigned short*)Aptr;
                uint4 raw = *(const uint4*)(A + ((unsigned)row << 7) + k0);
                float4 bA = *(const float4*)(bias_in + k0);
                float4 bB = *(const float4*)(bias_in + k0 + 4);
                float bb[8] = {bA.x, bA.y, bA.z, bA.w, bB.x, bB.y, bB.z, bB.w};
                unsigned rr[4] = {raw.x, raw.y, raw.z, raw.w};
#pragma unroll
                for (int jp = 0; jp < 4; jp++) {
                    float e0 = elu_(__uint_as_float(rr[jp] << 16)        + bb[jp * 2]);
                    float e1 = elu_(__uint_as_float(rr[jp] & 0xffff0000u) + bb[jp * 2 + 1]);
                    t.u[jp * 2]     = f2bf(e0);
                    t.u[jp * 2 + 1] = f2bf(e1);
                }
            } else {
                const float* A = (const float*)Aptr;
                float4 fA = *(const float4*)(A + ((unsigned)row << 7) + k0);
                float4 fB = *(const float4*)(A + ((unsigned)row << 7) + k0 + 4);
                t.u[0] = f2bf(fA.x); t.u[1] = f2bf(fA.y);
                t.u[2] = f2bf(fA.z); t.u[3] = f2bf(fA.w);
                t.u[4] = f2bf(fB.x); t.u[5] = f2bf(fB.y);
                t.u[6] = f2bf(fB.z); t.u[7] = f2bf(fB.w);
            }
        } else {
#pragma unroll
            for (int j = 0; j < 8; j++) t.u[j] = 0;
        }
        a[ks] = t.v;
    }
    float dl[2] = {0.f, 0.f}, dr[2] = {0.f, 0.f};   // per-head att-dot partials
#pragma unroll
    for (int ct = 0; ct < NT; ct++) {
        f4v cl = {0.f, 0.f, 0.f, 0.f}, cr = {0.f, 0.f, 0.f, 0.f};
#pragma unroll
        for (int ks = 0; ks < 4; ks++) {
            s8v bl = *(const s8v*)(Wlp + ((size_t)(ct * 4 + ks) * 64 + lane) * 8);
            s8v br = *(const s8v*)(Wrp + ((size_t)(ct * 4 + ks) * 64 + lane) * 8);
            cl = __builtin_amdgcn_mfma_f32_16x16x32_bf16(bl, a[ks], cl, 0, 0, 0);  // SWAPPED
            cr = __builtin_amdgcn_mfma_f32_16x16x32_bf16(br, a[ks], cr, 0, 0, 0);
        }
        int ch0 = ct * 16 + quad * 4;    // 4 consecutive out-channels this lane holds
        int hh = (H == 2) ? (ct >> 2) : 0;
        float4 av = *(const float4*)(att + ch0);
        dl[hh] += av.x * cl[0] + av.y * cl[1] + av.z * cl[2] + av.w * cl[3];
        dr[hh] += av.x * cr[0] + av.y * cr[1] + av.z * cr[2] + av.w * cr[3];
        if (row < n) {
            __half2 p0 = __floats2half2_rn(cl[0], cl[1]);
            __half2 p1 = __floats2half2_rn(cl[2], cl[3]);
            __half2 q0 = __floats2half2_rn(cr[0], cr[1]);
            __half2 q1 = __floats2half2_rn(cr[2], cr[3]);
            uint2 ov, orv;
            __builtin_memcpy(&ov.x, &p0, 4);  __builtin_memcpy(&ov.y, &p1, 4);
            __builtin_memcpy(&orv.x, &q0, 4); __builtin_memcpy(&orv.y, &q1, 4);
            *(uint2*)(outL + (unsigned)row * CO + ch0) = ov;
            *(uint2*)(outR + (unsigned)row * CO + ch0) = orv;
        }
    }
    // fold 4 quads -> per-node att-dot; premultiply 0.6*log2e for exp2 scoring
#pragma unroll
    for (int h = 0; h < H; h++) {
        float vl = dl[h], vr = dr[h];
        vl += __shfl_xor(vl, 16, 64); vl += __shfl_xor(vl, 32, 64);
        vr += __shfl_xor(vr, 16, 64); vr += __shfl_xor(vr, 32, 64);
        if (quad == 0 && row < n) {
            if (H == 2) {
                sl06[((unsigned)row << 1) + h] = (0.6f * LOG2E) * vl;
                sr06[((unsigned)row << 1) + h] = (0.6f * LOG2E) * vr;
            } else {
                sl06[row] = (0.6f * LOG2E) * vl;
                sr06[row] = (0.6f * LOG2E) * vr;
            }
        }
    }
}

// ---------------- CSR build ----------------
__global__ void hist_deg(const int* __restrict__ dstA, int E, int* __restrict__ deg) {
    int i = blockIdx.x * blockDim.x + threadIdx.x;
    if (i < E) atomicAdd(&deg[dstA[i]], 1);
}

__global__ void scan_block(const int* __restrict__ deg, int n,
                           int* __restrict__ rowptr, int* __restrict__ bsums) {
    __shared__ int tmp[256];
    int i = blockIdx.x * 256 + threadIdx.x;
    int v = (i < n) ? deg[i] : 0;
    tmp[threadIdx.x] = v;
    __syncthreads();
    for (int off = 1; off < 256; off <<= 1) {
        int t = (threadIdx.x >= (unsigned)off) ? tmp[threadIdx.x - off] : 0;
        __syncthreads();
        tmp[threadIdx.x] += t;
        __syncthreads();
    }
    if (i < n) rowptr[i] = tmp[threadIdx.x] - v;           // exclusive
    if (threadIdx.x == 255) bsums[blockIdx.x] = tmp[255];
}

__global__ void scan_sums(int* __restrict__ bsums, int nb) {
    __shared__ int tmp[256];
    int v = (threadIdx.x < (unsigned)nb) ? bsums[threadIdx.x] : 0;
    tmp[threadIdx.x] = v;
    __syncthreads();
    for (int off = 1; off < 256; off <<= 1) {
        int t = (threadIdx.x >= (unsigned)off) ? tmp[threadIdx.x - off] : 0;
        __syncthreads();
        tmp[threadIdx.x] += t;
        __syncthreads();
    }
    if (threadIdx.x < (unsigned)nb) bsums[threadIdx.x] = tmp[threadIdx.x] - v;
}

__global__ void scan_add(int* __restrict__ rowptr, int* __restrict__ cursor,
                         const int* __restrict__ bsums, int n, int E) {
    int i = blockIdx.x * 256 + threadIdx.x;
    if (i < n) {
        int v = rowptr[i] + bsums[i >> 8];
        rowptr[i] = v;
        cursor[i] = v;
    }
    if (i == n) rowptr[n] = E;
}

__global__ void csr_fill(const int* __restrict__ srcA, const int* __restrict__ dstA,
                         int E, int* __restrict__ cursor, int* __restrict__ csr_src) {
    int i = blockIdx.x * blockDim.x + threadIdx.x;
    if (i < E) {
        int pos = atomicAdd(&cursor[dstA[i]], 1);
        csr_src[pos] = srcA[i];
    }
}

// ---------------- fused GATv2 layer 1: 4 edges/iter, exp2 scoring -----------
// lane = [e:2][h:1][g:3]. score = sl06[s,h]+sr06[d,h]+fp16 dot (all pre-scaled
// by log2e). Output = raw acc/den (bias+ELU deferred to gemm<64> prologue).
__global__ void gat1_fused(const __half* __restrict__ xl, const __half* __restrict__ xr,
                           const float* __restrict__ sl06, const float* __restrict__ sr06,
                           const float* __restrict__ att,
                           const int* __restrict__ rowptr, const int* __restrict__ csr_src,
                           unsigned short* __restrict__ h1, int n) {
    int d = (blockIdx.x * blockDim.x + threadIdx.x) >> 6;
    if (d >= n) return;
    int lane = threadIdx.x & 63;
    int e = lane >> 4;                  // edge slot 0..3
    int h = (lane >> 3) & 1;            // head
    int off = h * 64 + (lane & 7) * 8;  // 8-channel base
    U4H xv; xv.u = *(const uint4*)(xr + (((unsigned)d << 7) + off));
    float4 aA = *(const float4*)(att + off);
    float4 aB = *(const float4*)(att + off + 4);
    const float S = 0.4f * LOG2E;
    __half2 a2[4];
    a2[0] = __floats2half2_rn(S * aA.x, S * aA.y);
    a2[1] = __floats2half2_rn(S * aA.z, S * aA.w);
    a2[2] = __floats2half2_rn(S * aB.x, S * aB.y);
    a2[3] = __floats2half2_rn(S * aB.z, S * aB.w);
    float srd = sr06[((unsigned)d << 1) + h];
    float c0 = 0.f, c1 = 0.f, c2 = 0.f, c3 = 0.f;
    float c4 = 0.f, c5 = 0.f, c6 = 0.f, c7 = 0.f, den = 0.f;
    int beg = rowptr[d], endp = rowptr[d + 1];
    for (int base = beg - 1; base < endp; base += 4) {
        int jj = base + e;
        bool valid = (jj < endp);
        int s = (jj >= beg && valid) ? csr_src[jj] : d;   // jj==beg-1 => self loop
        U4H lv; lv.u = *(const uint4*)(xl + (((unsigned)s << 7) + off));
        float sls = sl06[((unsigned)s << 1) + h];
        __half2 sc = __floats2half2_rn(0.f, 0.f);
        sc = __hfma2(a2[0], habs2_(__hadd2(lv.h[0], xv.h[0])), sc);
        sc = __hfma2(a2[1], habs2_(__hadd2(lv.h[1], xv.h[1])), sc);
        sc = __hfma2(a2[2], habs2_(__hadd2(lv.h[2], xv.h[2])), sc);
        sc = __hfma2(a2[3], habs2_(__hadd2(lv.h[3], xv.h[3])), sc);
        float v = __low2float(sc) + __high2float(sc);
        v += __shfl_xor(v, 1, 64); v += __shfl_xor(v, 2, 64); v += __shfl_xor(v, 4, 64);
        float p = valid ? exp2f(sls + srd + v) : 0.f;
        c0 = fmaf(__low2float(lv.h[0]),  p, c0);
        c1 = fmaf(__high2float(lv.h[0]), p, c1);
        c2 = fmaf(__low2float(lv.h[1]),  p, c2);
        c3 = fmaf(__high2float(lv.h[1]), p, c3);
        c4 = fmaf(__low2float(lv.h[2]),  p, c4);
        c5 = fmaf(__high2float(lv.h[2]), p, c5);
        c6 = fmaf(__low2float(lv.h[3]),  p, c6);
        c7 = fmaf(__high2float(lv.h[3]), p, c7);
        den += p;
    }
#pragma unroll
    for (int o = 16; o <= 32; o <<= 1) {
        c0 += __shfl_xor(c0, o, 64); c1 += __shfl_xor(c1, o, 64);
        c2 += __shfl_xor(c2, o, 64); c3 += __shfl_xor(c3, o, 64);
        c4 += __shfl_xor(c4, o, 64); c5 += __shfl_xor(c5, o, 64);
        c6 += __shfl_xor(c6, o, 64); c7 += __shfl_xor(c7, o, 64);
        den += __shfl_xor(den, o, 64);
    }
    if (e == 0) {
        float r = 1.f / den;
        uint4 out;
        out.x = (unsigned)f2bf(c0 * r) | ((unsigned)f2bf(c1 * r) << 16);
        out.y = (unsigned)f2bf(c2 * r) | ((unsigned)f2bf(c3 * r) << 16);
        out.z = (unsigned)f2bf(c4 * r) | ((unsigned)f2bf(c5 * r) << 16);
        out.w = (unsigned)f2bf(c6 * r) | ((unsigned)f2bf(c7 * r) << 16);
        *(uint4*)(h1 + (((unsigned)d << 7) + off)) = out;
    }
}

// ---------------- fused GATv2 layer 2: 8 edges/iter, exp2 scoring -----------
// lane = [e:3][g:3]. Output = raw acc/den (bias+ELU deferred to pool).
__global__ void gat2_fused(const __half* __restrict__ xl, const __half* __restrict__ xr,
                           const float* __restrict__ sl06, const float* __restrict__ sr06,
                           const float* __restrict__ att,
                           const int* __restrict__ rowptr, const int* __restrict__ csr_src,
                           float* __restrict__ h2, int n) {
    int d = (blockIdx.x * blockDim.x + threadIdx.x) >> 6;
    if (d >= n) return;
    int lane = threadIdx.x & 63;
    int e = lane >> 3;                  // edge slot 0..7
    int off = (lane & 7) * 8;           // 8-channel base
    U4H xv; xv.u = *(const uint4*)(xr + (((unsigned)d << 6) + off));
    float4 aA = *(const float4*)(att + off);
    float4 aB = *(const float4*)(att + off + 4);
    const float S = 0.4f * LOG2E;
    __half2 a2[4];
    a2[0] = __floats2half2_rn(S * aA.x, S * aA.y);
    a2[1] = __floats2half2_rn(S * aA.z, S * aA.w);
    a2[2] = __floats2half2_rn(S * aB.x, S * aB.y);
    a2[3] = __floats2half2_rn(S * aB.z, S * aB.w);
    float srd = sr06[d];
    float c0 = 0.f, c1 = 0.f, c2 = 0.f, c3 = 0.f;
    float c4 = 0.f, c5 = 0.f, c6 = 0.f, c7 = 0.f, den = 0.f;
    int beg = rowptr[d], endp = rowptr[d + 1];
    for (int base = beg - 1; base < endp; base += 8) {
        int jj = base + e;
        bool valid = (jj < endp);
        int s = (jj >= beg && valid) ? csr_src[jj] : d;
        U4H lv; lv.u = *(const uint4*)(xl + (((unsigned)s << 6) + off));
        float sls = sl06[s];
        __half2 sc = __floats2half2_rn(0.f, 0.f);
        sc = __hfma2(a2[0], habs2_(__hadd2(lv.h[0], xv.h[0])), sc);
        sc = __hfma2(a2[1], habs2_(__hadd2(lv.h[1], xv.h[1])), sc);
        sc = __hfma2(a2[2], habs2_(__hadd2(lv.h[2], xv.h[2])), sc);
        sc = __hfma2(a2[3], habs2_(__hadd2(lv.h[3], xv.h[3])), sc);
        float v = __low2float(sc) + __high2float(sc);
        v += __shfl_xor(v, 1, 64); v += __shfl_xor(v, 2, 64); v += __shfl_xor(v, 4, 64);
        float p = valid ? exp2f(sls + srd + v) : 0.f;
        c0 = fmaf(__low2float(lv.h[0]),  p, c0);
        c1 = fmaf(__high2float(lv.h[0]), p, c1);
        c2 = fmaf(__low2float(lv.h[1]),  p, c2);
        c3 = fmaf(__high2float(lv.h[1]), p, c3);
        c4 = fmaf(__low2float(lv.h[2]),  p, c4);
        c5 = fmaf(__high2float(lv.h[2]), p, c5);
        c6 = fmaf(__low2float(lv.h[3]),  p, c6);
        c7 = fmaf(__high2float(lv.h[3]), p, c7);
        den += p;
    }
#pragma unroll
    for (int o = 8; o <= 32; o <<= 1) {
        c0 += __shfl_xor(c0, o, 64); c1 += __shfl_xor(c1, o, 64);
        c2 += __shfl_xor(c2, o, 64); c3 += __shfl_xor(c3, o, 64);
        c4 += __shfl_xor(c4, o, 64); c5 += __shfl_xor(c5, o, 64);
        c6 += __shfl_xor(c6, o, 64); c7 += __shfl_xor(c7, o, 64);
        den += __shfl_xor(den, o, 64);
    }
    if (e == 0) {
        float r = 1.f / den;
        float4 A = {c0 * r, c1 * r, c2 * r, c3 * r};
        float4 B = {c4 * r, c5 * r, c6 * r, c7 * r};
        *(float4*)(h2 + (((unsigned)d << 6) + off))     = A;
        *(float4*)(h2 + (((unsigned)d << 6) + off + 4)) = B;
    }
}

// mean-pool over sorted batch; applies deferred elu(h + b2) while reading.
__global__ void pool_rle(const float* __restrict__ h, const float* __restrict__ b2,
                         const int* __restrict__ batch,
                         int n, int chunk, float* __restrict__ pooled,
                         float* __restrict__ counts) {
    int w = (blockIdx.x * blockDim.x + threadIdx.x) >> 6;
    int lane = threadIdx.x & 63;
    int start = w * chunk;
    int end = min(n, start + chunk);
    if (start >= end) return;
    float bv = b2[lane];
    int cur = batch[start];
    float acc = 0.f, cnt = 0.f;
    for (int node = start; node < end; node++) {
        int g = batch[node];
        if (g != cur) {
            atomicAdd(&pooled[(size_t)cur * 64 + lane], acc);
            if (lane == 0) atomicAdd(&counts[cur], cnt);
            acc = 0.f; cnt = 0.f; cur = g;
        }
        acc += elu_(h[((unsigned)node << 6) + lane] + bv);
        cnt += 1.f;
    }
    atomicAdd(&pooled[(size_t)cur * 64 + lane], acc);
    if (lane == 0) atomicAdd(&counts[cur], cnt);
}

__global__ void head(const float* __restrict__ pooled, const float* __restrict__ counts,
                     const float* __restrict__ Wlin, const float* __restrict__ blin,
                     float* __restrict__ out, int NC) {
    int g = blockIdx.x;
    int lane = threadIdx.x;
    float cnt = fmaxf(counts[g], 1.f);
    float v = pooled[(size_t)g * 64 + lane] / cnt;
    for (int j = 0; j < NC; j++) {
        float t = v * Wlin[lane * NC + j];
        for (int off = 32; off > 0; off >>= 1) t += __shfl_down(t, off, 64);
        if (lane == 0) out[g * NC + j] = t + blin[j];
    }
}

extern "C" void kernel_launch(void* const* d_in, const int* in_sizes, int n_in,
                              void* d_out, int out_size, void* d_ws, size_t ws_size,
                              hipStream_t stream) {
    const float* x    = (const float*)d_in[0];
    const int*   ei   = (const int*)d_in[1];
    const int*   batch= (const int*)d_in[2];
    const float* Wl1  = (const float*)d_in[3];
    const float* Wr1  = (const float*)d_in[4];
    const float* att1 = (const float*)d_in[5];
    const float* b1   = (const float*)d_in[6];
    const float* Wl2  = (const float*)d_in[7];
    const float* Wr2  = (const float*)d_in[8];
    const float* att2 = (const float*)d_in[9];
    const float* b2   = (const float*)d_in[10];
    const float* Wlin = (const float*)d_in[11];
    const float* blin = (const float*)d_in[12];

    const int n    = in_sizes[0] / 128;   // 50000
    const int E    = in_sizes[1] / 2;     // 600000
    const int NC   = in_sizes[12];        // 10
    const int NG   = out_size / NC;       // 64

    const int* srcA = ei;
    const int* dstA = ei + E;

    // ---- workspace layout (bytes). Aliasing: xl2+xr2 fill xl1's region,
    //      h2 fills xr1's. h1 (raw bf16) is kept live through gemm_dual<64>.
    uint8_t* w = (uint8_t*)d_ws;
    const size_t rowB = (size_t)n * 128 * 2;     // one N x 128 16-bit tensor
    __half*         xl1 = (__half*)w;
    __half*         xr1 = (__half*)(w + rowB);
    unsigned short* h1  = (unsigned short*)(w + 2 * rowB);
    __half*         xl2 = (__half*)w;                           // n*64 fp16
    __half*         xr2 = (__half*)(w + (size_t)n * 64 * 2);
    float*          h2  = (float*)(w + rowB);                   // n*64 fp32
    uint8_t* fx = w + 3 * rowB;
    unsigned short* Wl1p = (unsigned short*)fx;            fx += 16384 * 2;
    unsigned short* Wr1p = (unsigned short*)fx;            fx += 16384 * 2;
    unsigned short* Wl2p = (unsigned short*)fx;            fx += 8192 * 2;
    unsigned short* Wr2p = (unsigned short*)fx;            fx += 8192 * 2;
    float* sl1 = (float*)fx;                               fx += (size_t)n * 2 * 4;
    float* sr1 = (float*)fx;                               fx += (size_t)n * 2 * 4;
    float* sl2 = (float*)fx;                               fx += (size_t)n * 4;
    float* sr2 = (float*)fx;                               fx += (size_t)n * 4;
    float* pooled = (float*)fx;                            fx += (size_t)NG * 64 * 4;
    float* counts = (float*)fx;                            fx += (size_t)NG * 4;
    int* rowptr  = (int*)fx;                               fx += (size_t)(n + 1) * 4;
    int* deg     = (int*)fx;                               fx += (size_t)n * 4;
    int* cursor  = (int*)fx;                               fx += (size_t)n * 4;
    int* bsums   = (int*)fx;                               fx += 256 * 4;
    int* csr_src = (int*)fx;                               fx += (size_t)E * 4;
    if (ws_size < (size_t)(fx - (uint8_t*)d_ws)) return;   // bail visibly

    const int nb = (n + 255) / 256;

    // ---- weight packing + CSR build ----
    pack_weights<<<24, 256, 0, stream>>>(Wl1, Wr1, Wl2, Wr2, Wl1p, Wr1p, Wl2p, Wr2p);
    hipMemsetAsync(deg, 0, (size_t)n * sizeof(int), stream);
    hist_deg<<<(E + 255) / 256, 256, 0, stream>>>(dstA, E, deg);
    scan_block<<<nb, 256, 0, stream>>>(deg, n, rowptr, bsums);
    scan_sums<<<1, 256, 0, stream>>>(bsums, nb);
    scan_add<<<(n + 256) / 256, 256, 0, stream>>>(rowptr, cursor, bsums, n, E);
    csr_fill<<<(E + 255) / 256, 256, 0, stream>>>(srcA, dstA, E, cursor, csr_src);

    const int mblocks = (n + 63) / 64;       // MFMA gemm: 64 nodes/block
    const int dblocks = (n + 3) / 4;         // 4 dst-waves per 256-thread block

    // ---- layer 1 ----
    gemm_dual<128, false><<<mblocks, 256, 0, stream>>>(x, Wl1p, Wr1p, xl1, xr1,
                                                       att1, b1, sl1, sr1, n);
    gat1_fused<<<dblocks, 256, 0, stream>>>(xl1, xr1, sl1, sr1, att1,
                                            rowptr, csr_src, h1, n);

    // ---- layer 2 (gemm applies elu(h1 + b1) while loading node fragments) ----
    gemm_dual<64, true><<<mblocks, 256, 0, stream>>>(h1, Wl2p, Wr2p, xl2, xr2,
                                                     att2, b1, sl2, sr2, n);
    gat2_fused<<<dblocks, 256, 0, stream>>>(xl2, xr2, sl2, sr2, att2,
                                            rowptr, csr_src, h2, n);

    // ---- pool (applies elu(h2 + b2)) + head ----
    hipMemsetAsync(pooled, 0, (size_t)(NG * 64 + NG) * sizeof(float), stream);
    {
        const int nwaves = 1024;
        const int chunk = (n + nwaves - 1) / nwaves;
        pool_rle<<<256, 256, 0, stream>>>(h2, b2, batch, n, chunk, pooled, counts);
    }
    head<<<NG, 64, 0, stream>>>(pooled, counts, Wlin, blin, (float*)d_out, NC);
}